// Round 9
// baseline (1419.126 us; speedup 1.0000x reference)
//
#include <hip/hip_runtime.h>
#include <hip/hip_bf16.h>
#include <math.h>

#define BB 8
#define NN 2048
#define KK 20
#define XCCH 512
#define NSLOT 64
#define LEPS 1e-5f

typedef __attribute__((ext_vector_type(8))) short s8v;
typedef __attribute__((ext_vector_type(8))) _Float16 h8v;
typedef __attribute__((ext_vector_type(4))) float f32x4;

__device__ __forceinline__ float lrelu(float x){ return x >= 0.f ? x : 0.2f*x; }

__device__ __forceinline__ s8v bsub8(s8v a, s8v b){
  union U { s8v s; __hip_bfloat162 h[4]; } A, B, R;
  A.s = a; B.s = b;
  #pragma unroll
  for (int i=0;i<4;i++) R.h[i] = __hsub2(A.h[i], B.h[i]);
  return R.s;
}

// ---------- transpose x (B,3,N) -> xt0 (B*N,4) fp32 ----------
__global__ __launch_bounds__(256) void k_transpose(const float* __restrict__ x, float* __restrict__ xt){
  int i = blockIdx.x*256 + threadIdx.x;
  if (i >= BB*NN) return;
  int b = i >> 11, n = i & (NN-1);
  float4 v;
  v.x = x[(b*3+0)*NN + n];
  v.y = x[(b*3+1)*NN + n];
  v.z = x[(b*3+2)*NN + n];
  v.w = 0.f;
  reinterpret_cast<float4*>(xt)[i] = v;
}

// ---------- weight fp32 -> bf16 slice with K padding ----------
__global__ __launch_bounds__(256) void k_cvtw(const float* __restrict__ W, __hip_bfloat16* __restrict__ Wb,
                                              int Cs, int coff, int Ccnt, int Cpad, int total){
  int i = blockIdx.x*256 + threadIdx.x;
  if (i >= total) return;
  int o = i / Cpad, c = i - o*Cpad;
  Wb[i] = (c < Ccnt) ? __float2bfloat16(W[(size_t)o*Cs + coff + c]) : __float2bfloat16(0.f);
}

// ---------- split P fp32 -> h/m/l f16 (Cpad cols, zero-padded); h+m+l ~ x to 2^-33 ----------
__global__ __launch_bounds__(256) void k_split(const float* __restrict__ P, int stride, int Ci, int Cpad,
    _Float16* __restrict__ Ph, _Float16* __restrict__ Pm, _Float16* __restrict__ Pl){
  int i = blockIdx.x*256 + threadIdx.x;
  if (i >= BB*NN*Cpad) return;
  int p = i / Cpad, c = i - p*Cpad;
  float v = (c < Ci) ? P[(size_t)p*stride + c] : 0.f;
  _Float16 h = (_Float16)v;
  float r1 = v - (float)h;
  _Float16 m = (_Float16)r1;
  float r2 = r1 - (float)m;
  Ph[i] = h;
  Pm[i] = m;
  Pl[i] = (_Float16)r2;
}

// ---------- squared norms from the split representation ----------
__global__ __launch_bounds__(256) void k_sqs(const _Float16* __restrict__ Ph,
    const _Float16* __restrict__ Pm, const _Float16* __restrict__ Pl,
    int Cpad, float* __restrict__ sq){
  int i = blockIdx.x*256 + threadIdx.x;
  if (i >= BB*NN) return;
  const _Float16* ph = Ph + (size_t)i*Cpad;
  const _Float16* pm = Pm + (size_t)i*Cpad;
  const _Float16* pl = Pl + (size_t)i*Cpad;
  float s = 0.f;
  for (int c = 0; c < Cpad; ++c){
    float v = (float)ph[c] + (float)pm[c] + (float)pl[c];
    s += v*v;
  }
  sq[i] = s;
}

// ---------- MFMA pairwise score: pd = 2*dot - sq_n - sq_m ----------
// dot via 3-term f16 split, 6 products (hh,hm,mh,hl,lh,mm) -> error ~2^-33, below fp32 ulp.
// 128x128 tile, 4 waves; wave w -> rows [w*32, w*32+32), all 8 col-strips.
__global__ __launch_bounds__(256) void k_distm(
    const _Float16* __restrict__ Ph, const _Float16* __restrict__ Pm, const _Float16* __restrict__ Pl,
    int Cpad, int nchunk, const float* __restrict__ sq, float* __restrict__ pd)
{
  __shared__ _Float16 Ah[128*40];
  __shared__ _Float16 Am[128*40];
  __shared__ _Float16 Al[128*40];
  __shared__ _Float16 Bh[128*40];
  __shared__ _Float16 Bm[128*40];
  __shared__ _Float16 Bl[128*40];
  int t = threadIdx.x;
  int w = t >> 6, lane = t & 63, m = lane & 15, quad = lane >> 4;
  int b = blockIdx.z;
  int n0 = blockIdx.y * 128, m0 = blockIdx.x * 128;
  const _Float16* PhB = Ph + (size_t)b*NN*Cpad;
  const _Float16* PmB = Pm + (size_t)b*NN*Cpad;
  const _Float16* PlB = Pl + (size_t)b*NN*Cpad;
  f32x4 acc[2][8];
  #pragma unroll
  for (int s=0;s<2;s++)
    #pragma unroll
    for (int j=0;j<8;j++){ f32x4 z = {0.f,0.f,0.f,0.f}; acc[s][j] = z; }
  int r = t >> 1;
  int sg0 = t & 1;
  for (int ch=0; ch<nchunk; ++ch){
    int c0 = ch*32;
    #pragma unroll
    for (int k=0;k<2;k++){
      int seg = sg0 + 2*k;
      int go = c0 + seg*8;
      size_t an = (size_t)(n0+r)*Cpad + go;
      size_t bm = (size_t)(m0+r)*Cpad + go;
      *(h8v*)&Ah[r*40 + seg*8] = *(const h8v*)&PhB[an];
      *(h8v*)&Am[r*40 + seg*8] = *(const h8v*)&PmB[an];
      *(h8v*)&Al[r*40 + seg*8] = *(const h8v*)&PlB[an];
      *(h8v*)&Bh[r*40 + seg*8] = *(const h8v*)&PhB[bm];
      *(h8v*)&Bm[r*40 + seg*8] = *(const h8v*)&PmB[bm];
      *(h8v*)&Bl[r*40 + seg*8] = *(const h8v*)&PlB[bm];
    }
    __syncthreads();
    h8v ah0 = *(const h8v*)&Ah[(w*32 + m)*40 + quad*8];
    h8v am0 = *(const h8v*)&Am[(w*32 + m)*40 + quad*8];
    h8v al0 = *(const h8v*)&Al[(w*32 + m)*40 + quad*8];
    h8v ah1 = *(const h8v*)&Ah[(w*32 + 16 + m)*40 + quad*8];
    h8v am1 = *(const h8v*)&Am[(w*32 + 16 + m)*40 + quad*8];
    h8v al1 = *(const h8v*)&Al[(w*32 + 16 + m)*40 + quad*8];
    #pragma unroll
    for (int j=0;j<8;j++){
      h8v bh = *(const h8v*)&Bh[(j*16 + m)*40 + quad*8];
      h8v bm = *(const h8v*)&Bm[(j*16 + m)*40 + quad*8];
      h8v bl = *(const h8v*)&Bl[(j*16 + m)*40 + quad*8];
      acc[0][j] = __builtin_amdgcn_mfma_f32_16x16x32_f16(ah0, bh, acc[0][j], 0, 0, 0);
      acc[0][j] = __builtin_amdgcn_mfma_f32_16x16x32_f16(ah0, bm, acc[0][j], 0, 0, 0);
      acc[0][j] = __builtin_amdgcn_mfma_f32_16x16x32_f16(am0, bh, acc[0][j], 0, 0, 0);
      acc[0][j] = __builtin_amdgcn_mfma_f32_16x16x32_f16(ah0, bl, acc[0][j], 0, 0, 0);
      acc[0][j] = __builtin_amdgcn_mfma_f32_16x16x32_f16(al0, bh, acc[0][j], 0, 0, 0);
      acc[0][j] = __builtin_amdgcn_mfma_f32_16x16x32_f16(am0, bm, acc[0][j], 0, 0, 0);
      acc[1][j] = __builtin_amdgcn_mfma_f32_16x16x32_f16(ah1, bh, acc[1][j], 0, 0, 0);
      acc[1][j] = __builtin_amdgcn_mfma_f32_16x16x32_f16(ah1, bm, acc[1][j], 0, 0, 0);
      acc[1][j] = __builtin_amdgcn_mfma_f32_16x16x32_f16(am1, bh, acc[1][j], 0, 0, 0);
      acc[1][j] = __builtin_amdgcn_mfma_f32_16x16x32_f16(ah1, bl, acc[1][j], 0, 0, 0);
      acc[1][j] = __builtin_amdgcn_mfma_f32_16x16x32_f16(al1, bh, acc[1][j], 0, 0, 0);
      acc[1][j] = __builtin_amdgcn_mfma_f32_16x16x32_f16(am1, bm, acc[1][j], 0, 0, 0);
    }
    __syncthreads();
  }
  float sqm_[8];
  #pragma unroll
  for (int j=0;j<8;j++) sqm_[j] = sq[b*NN + m0 + j*16 + m];
  #pragma unroll
  for (int s=0;s<2;s++){
    int rbase = w*32 + s*16 + quad*4;
    #pragma unroll
    for (int rg=0; rg<4; rg++){
      float sqn = sq[b*NN + n0 + rbase + rg];
      size_t rowoff = ((size_t)b*NN + n0 + rbase + rg)*NN + m0 + m;
      #pragma unroll
      for (int j=0;j<8;j++){
        pd[rowoff + j*16] = 2.f*acc[s][j][rg] - sqn - sqm_[j];
      }
    }
  }
}

// ---------- top-20 per row: one wave per row, no barriers ----------
__global__ __launch_bounds__(256) void k_topk(const float* __restrict__ pd, int* __restrict__ idxo){
  int t = threadIdx.x;
  int l = t & 63;
  int row = blockIdx.x*4 + (t >> 6);
  const float4* rp = (const float4*)(pd + (size_t)row*NN);
  float r[32];
  #pragma unroll
  for (int j=0;j<8;j++){
    float4 v = rp[j*64 + l];
    r[j*4+0]=v.x; r[j*4+1]=v.y; r[j*4+2]=v.z; r[j*4+3]=v.w;
  }
  float bv = r[0]; int bi = 0;
  #pragma unroll
  for (int u=1;u<32;u++){ if (r[u] > bv){ bv = r[u]; bi = u; } }
  int myout = 0;
  for (int it=0; it<KK; ++it){
    int gidx = ((bi >> 2) << 8) | (l << 2) | (bi & 3);
    float v = bv; int gi = gidx;
    #pragma unroll
    for (int off=1; off<64; off<<=1){
      float ov = __shfl_xor(v, off);
      int og = __shfl_xor(gi, off);
      if (ov > v || (ov == v && og < gi)){ v = ov; gi = og; }
    }
    if (l == it) myout = gi;
    if (gi == gidx){
      r[bi] = -3.4e38f;
      bv = r[0]; bi = 0;
      #pragma unroll
      for (int u=1;u<32;u++){ if (r[u] > bv){ bv = r[u]; bi = u; } }
    }
  }
  if (l < KK) idxo[row*KK + l] = myout;
}

// ---------- ctr part: register-tiled GEMM, 64 pts x 64 outs per block ----------
__global__ __launch_bounds__(256) void k_ctr(const float* __restrict__ P, int stride, int Ci,
    const float* __restrict__ W, int twoCi, float* __restrict__ ctrb){
  __shared__ float Pt[64*17];
  __shared__ float Wt[64*17];
  int t = threadIdx.x, ty = t >> 4, tx = t & 15;
  int p0 = blockIdx.x*64, o0 = blockIdx.y*64;
  float acc[4][4];
  #pragma unroll
  for (int i=0;i<4;i++)
    #pragma unroll
    for (int j=0;j<4;j++) acc[i][j]=0.f;
  for (int c0 = 0; c0 < Ci; c0 += 16){
    #pragma unroll
    for (int q=0;q<4;q++){
      int e = t + 256*q;
      int r = e >> 4, cc = e & 15;
      int c = c0 + cc;
      bool ok = (c < Ci);
      Pt[r*17+cc] = ok ? P[(size_t)(p0+r)*stride + c] : 0.f;
      Wt[r*17+cc] = ok ? W[(size_t)(o0+r)*twoCi + c] : 0.f;
    }
    __syncthreads();
    #pragma unroll
    for (int j=0;j<16;j++){
      float a[4], bv[4];
      #pragma unroll
      for (int i=0;i<4;i++) a[i]  = Pt[(ty*4+i)*17 + j];
      #pragma unroll
      for (int i=0;i<4;i++) bv[i] = Wt[(tx*4+i)*17 + j];
      #pragma unroll
      for (int i=0;i<4;i++)
        #pragma unroll
        for (int jj=0;jj<4;jj++) acc[i][jj] += a[i]*bv[jj];
    }
    __syncthreads();
  }
  #pragma unroll
  for (int i=0;i<4;i++){
    *(float4*)&ctrb[(size_t)(p0+ty*4+i)*256 + o0 + tx*4] =
      make_float4(acc[i][0], acc[i][1], acc[i][2], acc[i][3]);
  }
}

// ---------- fp32 diff-conv (layers 1-3): 8 points (160 rows) x 64 outs per block ----------
__global__ __launch_bounds__(256) void k_conv(const float* __restrict__ P, int stride, int Ci,
    const float* __restrict__ W, int Oi, const int* __restrict__ idxg,
    const float* __restrict__ ctrb,
    float* __restrict__ ymax, float* __restrict__ ymin,
    float* __restrict__ chsum, float* __restrict__ chsq){
  __shared__ int lidx[160];
  __shared__ float ft[160*17];
  __shared__ float wt[16*68];
  int t = threadIdx.x;
  int blk = blockIdx.x;
  int b = blk >> 8;
  int n0 = (blk & 255) * 8;
  int o0 = blockIdx.y*64;
  if (t < 160) lidx[t] = idxg[((size_t)b*NN + n0)*KK + t];
  int tr = t >> 3, tc = t & 7;
  int twoCi = 2*Ci;
  const float* Pb = P + (size_t)b*NN*stride;
  float acc[5][8];
  #pragma unroll
  for (int i=0;i<5;i++)
    #pragma unroll
    for (int j=0;j<8;j++) acc[i][j]=0.f;
  int nchunks = (Ci + 15)/16;
  __syncthreads();
  for (int ch=0; ch<nchunks; ++ch){
    int c0 = ch*16;
    #pragma unroll
    for (int q=0;q<10;q++){
      int e = t + 256*q;
      int r = e >> 4, cc = e & 15;
      int c = c0 + cc;
      int n = n0 + r/20;
      float v = 0.f;
      if (c < Ci){
        int nbn = lidx[r];
        v = Pb[(size_t)nbn*stride + c] - Pb[(size_t)n*stride + c];
      }
      ft[r*17+cc] = v;
    }
    #pragma unroll
    for (int q=0;q<4;q++){
      int e = t + 256*q;
      int oi = e >> 4, cc = e & 15;
      int c = c0 + cc;
      wt[cc*68 + oi] = (c < Ci) ? W[(size_t)(o0+oi)*twoCi + Ci + c] : 0.f;
    }
    __syncthreads();
    #pragma unroll
    for (int j=0;j<16;j++){
      float4 w0 = *reinterpret_cast<const float4*>(&wt[j*68 + tc*8]);
      float4 w1 = *reinterpret_cast<const float4*>(&wt[j*68 + tc*8 + 4]);
      #pragma unroll
      for (int i=0;i<5;i++){
        float a = ft[(tr*5+i)*17 + j];
        acc[i][0] += a*w0.x;
        acc[i][1] += a*w0.y;
        acc[i][2] += a*w0.z;
        acc[i][3] += a*w0.w;
        acc[i][4] += a*w1.x;
        acc[i][5] += a*w1.y;
        acc[i][6] += a*w1.z;
        acc[i][7] += a*w1.w;
      }
    }
    __syncthreads();
  }
  int pt = tr >> 2;
  int n = n0 + pt;
  const float4 cv0 = *(const float4*)&ctrb[((size_t)b*NN + n)*256 + o0 + tc*8];
  const float4 cv1 = *(const float4*)&ctrb[((size_t)b*NN + n)*256 + o0 + tc*8 + 4];
  float cv[8] = {cv0.x,cv0.y,cv0.z,cv0.w,cv1.x,cv1.y,cv1.z,cv1.w};
  float mx[8], mn[8], sm[8], s2[8];
  #pragma unroll
  for (int jj=0;jj<8;jj++){
    float cc = cv[jj];
    float y0 = acc[0][jj] + cc;
    float a_mx = y0, a_mn = y0, a_s = y0, a_s2 = y0*y0;
    #pragma unroll
    for (int i=1;i<5;i++){
      float y = acc[i][jj] + cc;
      a_mx = fmaxf(a_mx,y); a_mn = fminf(a_mn,y); a_s += y; a_s2 += y*y;
    }
    mx[jj]=a_mx; mn[jj]=a_mn; sm[jj]=a_s; s2[jj]=a_s2;
  }
  #pragma unroll
  for (int jj=0;jj<8;jj++){
    mx[jj] = fmaxf(mx[jj], __shfl_xor(mx[jj], 8));
    mn[jj] = fminf(mn[jj], __shfl_xor(mn[jj], 8));
    sm[jj] += __shfl_xor(sm[jj], 8);
    s2[jj] += __shfl_xor(s2[jj], 8);
    mx[jj] = fmaxf(mx[jj], __shfl_xor(mx[jj], 16));
    mn[jj] = fminf(mn[jj], __shfl_xor(mn[jj], 16));
    sm[jj] += __shfl_xor(sm[jj], 16);
    s2[jj] += __shfl_xor(s2[jj], 16);
  }
  if ((tr & 3) == 0){
    size_t base = ((size_t)b*NN + n)*256 + o0 + tc*8;
    *(float4*)&ymax[base]   = make_float4(mx[0],mx[1],mx[2],mx[3]);
    *(float4*)&ymax[base+4] = make_float4(mx[4],mx[5],mx[6],mx[7]);
    *(float4*)&ymin[base]   = make_float4(mn[0],mn[1],mn[2],mn[3]);
    *(float4*)&ymin[base+4] = make_float4(mn[4],mn[5],mn[6],mn[7]);
  }
  #pragma unroll
  for (int jj=0;jj<8;jj++){
    sm[jj] += __shfl_xor(sm[jj], 32);
    s2[jj] += __shfl_xor(s2[jj], 32);
  }
  if ((tr & 7) == 0){
    int slot = blk & (NSLOT-1);
    #pragma unroll
    for (int jj=0;jj<8;jj++){
      int o = o0 + tc*8 + jj;
      atomicAdd(&chsum[slot*256 + o], sm[jj]);
      atomicAdd(&chsq [slot*256 + o], s2[jj]);
    }
  }
}

// ---------- MFMA diff-conv (layer 4): K = 128; epilogue adds fp32 ctr part ----------
__global__ __launch_bounds__(256) void k_convm(
    const __hip_bfloat16* __restrict__ PB, int stride,
    const __hip_bfloat16* __restrict__ Wd, int nchunk,
    const int* __restrict__ idxg, const float* __restrict__ ctrb,
    float* __restrict__ ymax, float* __restrict__ ymin,
    float* __restrict__ chsum, float* __restrict__ chsq)
{
  __shared__ __align__(16) char smem[40960];
  __hip_bfloat16* As = (__hip_bfloat16*)smem;
  float* redmx = (float*)smem;
  float* redmn = (float*)(smem + 20480);
  __shared__ int lidx[320];
  int t = threadIdx.x;
  int w = t >> 6, lane = t & 63, m = lane & 15, quad = lane >> 4;
  int p0 = blockIdx.x * 16;
  int b  = p0 >> 11;
  int o0 = blockIdx.y * 64;
  int Kpad = nchunk * 32;
  for (int q = t; q < 320; q += 256) lidx[q] = idxg[p0*KK + q];
  f32x4 acc[20];
  #pragma unroll
  for (int s=0;s<20;s++){ f32x4 z = {0.f,0.f,0.f,0.f}; acc[s] = z; }
  __syncthreads();

  const __hip_bfloat16* wrow = Wd + (size_t)(o0 + w*16 + m)*Kpad + quad*8;

  unsigned offn[5], offnb[5]; int lo[5];
  #pragma unroll
  for (int q=0;q<5;q++){
    int s = t + 256*q;
    int rr = s >> 2, seg = s & 3;
    int pp = (rr*6554) >> 17;
    int n_g  = p0 + pp;
    int nb_g = (b<<11) + lidx[rr];
    offn[q]  = (unsigned)n_g*stride  + seg*8;
    offnb[q] = (unsigned)nb_g*stride + seg*8;
    lo[q] = rr*40 + seg*8;
  }
  for (int ch=0; ch<nchunk; ++ch){
    int c0 = ch*32;
    #pragma unroll
    for (int q=0;q<5;q++){
      s8v a  = *(const s8v*)&PB[offnb[q] + c0];
      s8v bb = *(const s8v*)&PB[offn[q]  + c0];
      *(s8v*)&As[lo[q]] = bsub8(a, bb);
    }
    __syncthreads();
    s8v bf = *(const s8v*)(wrow + c0);
    #pragma unroll
    for (int s=0;s<20;s++){
      s8v af = *(const s8v*)&As[(s*16+m)*40 + quad*8];
      acc[s] = __builtin_amdgcn_mfma_f32_16x16x32_bf16(af, bf, acc[s], 0, 0, 0);
    }
    __syncthreads();
  }

  int col = o0 + w*16 + m;
  float sm = 0.f, sq = 0.f;
  #pragma unroll
  for (int s=0;s<20;s++){
    int row0 = s*16 + quad*4;
    int pp = (row0*6554) >> 17;
    float cc = ctrb[(size_t)(p0+pp)*256 + col];
    f32x4 a = acc[s];
    a.x += cc; a.y += cc; a.z += cc; a.w += cc;
    float mx = fmaxf(fmaxf(a.x,a.y), fmaxf(a.z,a.w));
    float mn = fminf(fminf(a.x,a.y), fminf(a.z,a.w));
    sm += a.x + a.y + a.z + a.w;
    sq += a.x*a.x + a.y*a.y + a.z*a.z + a.w*a.w;
    int gq = s*4 + quad;
    redmx[gq*64 + w*16 + m] = mx;
    redmn[gq*64 + w*16 + m] = mn;
  }
  sm += __shfl_xor(sm, 16); sq += __shfl_xor(sq, 16);
  sm += __shfl_xor(sm, 32); sq += __shfl_xor(sq, 32);
  if (quad == 0){
    int slot = blockIdx.x & (NSLOT-1);
    atomicAdd(&chsum[slot*256 + col], sm);
    atomicAdd(&chsq [slot*256 + col], sq);
  }
  __syncthreads();
  #pragma unroll
  for (int q=0;q<4;q++){
    int i = t + 256*q;
    int pp = i >> 6, c2 = i & 63;
    float mx = redmx[(pp*5)*64 + c2];
    float mn = redmn[(pp*5)*64 + c2];
    #pragma unroll
    for (int u=1;u<5;u++){
      mx = fmaxf(mx, redmx[(pp*5+u)*64 + c2]);
      mn = fminf(mn, redmn[(pp*5+u)*64 + c2]);
    }
    size_t base = ((size_t)(p0+pp))*256 + o0 + c2;
    ymax[base] = mx;
    ymin[base] = mn;
  }
}

// ---------- BN stats finalize ----------
__global__ __launch_bounds__(256) void k_bnstats(const float* __restrict__ chsum, const float* __restrict__ chsq,
    const float* __restrict__ g, const float* __restrict__ bet,
    float* __restrict__ scl, float* __restrict__ shf, int Oi){
  int o = threadIdx.x;
  if (o >= Oi) return;
  float s=0.f, s2=0.f;
  for (int u=0;u<NSLOT;u++){ s += chsum[u*256+o]; s2 += chsq[u*256+o]; }
  float cnt = (float)(BB*NN*KK);
  float mean = s/cnt;
  float var = s2/cnt - mean*mean;
  float sc = g[o] / sqrtf(var + LEPS);
  scl[o] = sc;
  shf[o] = bet[o] - mean*sc;
}

// ---------- apply BN+LReLU, write fp32 xc + bf16 xcb ----------
__global__ __launch_bounds__(256) void k_apply(const float* __restrict__ ymax, const float* __restrict__ ymin,
    const float* __restrict__ scl, const float* __restrict__ shf,
    float* __restrict__ xc, __hip_bfloat16* __restrict__ xcb, int off, int Oi){
  int i = blockIdx.x*256 + threadIdx.x;
  if (i >= BB*NN*Oi) return;
  int o = i & (Oi-1);
  size_t p = (size_t)((unsigned)i / (unsigned)Oi);
  float sc = scl[o];
  float v = (sc >= 0.f) ? ymax[p*256+o] : ymin[p*256+o];
  float r = lrelu(v*sc + shf[o]);
  xc [p*XCCH + off + o] = r;
  xcb[p*XCCH + off + o] = __float2bfloat16(r);
}

// ---------- MFMA conv5 ----------
__global__ __launch_bounds__(256) void k_conv5m(const __hip_bfloat16* __restrict__ xcb,
    const __hip_bfloat16* __restrict__ w5b,
    float* __restrict__ pmax, float* __restrict__ pmin,
    float* __restrict__ psum, float* __restrict__ psq)
{
  int t = threadIdx.x, w = t >> 6, lane = t & 63, m = lane & 15, quad = lane >> 4;
  int nbk = blockIdx.x, b = blockIdx.z;
  int o0 = blockIdx.y * 64;
  int n0 = nbk * 256;
  const __hip_bfloat16* arow = xcb + (size_t)(b*NN + n0 + m)*XCCH + quad*8;
  const __hip_bfloat16* brow = w5b + (size_t)(o0 + w*16 + m)*XCCH + quad*8;
  f32x4 acc[16];
  #pragma unroll
  for (int s=0;s<16;s++){ f32x4 z = {0.f,0.f,0.f,0.f}; acc[s] = z; }
  for (int ch=0; ch<16; ++ch){
    int c0 = ch*32;
    s8v bf = *(const s8v*)(brow + c0);
    #pragma unroll
    for (int s=0;s<16;s++){
      s8v af = *(const s8v*)(arow + (size_t)s*16*XCCH + c0);
      acc[s] = __builtin_amdgcn_mfma_f32_16x16x32_bf16(af, bf, acc[s], 0, 0, 0);
    }
  }
  float mx = -3.4e38f, mn = 3.4e38f, sm = 0.f, sq = 0.f;
  #pragma unroll
  for (int s=0;s<16;s++){
    f32x4 a = acc[s];
    mx = fmaxf(mx, fmaxf(fmaxf(a.x,a.y), fmaxf(a.z,a.w)));
    mn = fminf(mn, fminf(fminf(a.x,a.y), fminf(a.z,a.w)));
    sm += a.x + a.y + a.z + a.w;
    sq += a.x*a.x + a.y*a.y + a.z*a.z + a.w*a.w;
  }
  #pragma unroll
  for (int off=16; off<=32; off<<=1){
    mx = fmaxf(mx, __shfl_xor(mx, off));
    mn = fminf(mn, __shfl_xor(mn, off));
    sm += __shfl_xor(sm, off);
    sq += __shfl_xor(sq, off);
  }
  if (quad == 0){
    size_t ii = ((size_t)b*1024 + o0 + w*16 + m)*8 + nbk;
    pmax[ii] = mx; pmin[ii] = mn; psum[ii] = sm; psq[ii] = sq;
  }
}

__global__ __launch_bounds__(256) void k_stats5(const float* __restrict__ psum, const float* __restrict__ psq,
    const float* __restrict__ g5, const float* __restrict__ b5,
    float* __restrict__ sc5, float* __restrict__ sh5){
  int o = blockIdx.x*256 + threadIdx.x;
  float s=0.f, s2=0.f;
  for (int b=0;b<BB;b++){
    const float* ps = &psum[((size_t)b*1024 + o)*8];
    const float* pq = &psq [((size_t)b*1024 + o)*8];
    #pragma unroll
    for (int u=0;u<8;u++){ s += ps[u]; s2 += pq[u]; }
  }
  float cnt = (float)(BB*NN);
  float mean = s/cnt;
  float var = s2/cnt - mean*mean;
  float sc = g5[o] / sqrtf(var + LEPS);
  sc5[o] = sc;
  sh5[o] = b5[o] - mean*sc;
}

__global__ __launch_bounds__(256) void k_apply5(const float* __restrict__ pmax, const float* __restrict__ pmin,
    const float* __restrict__ sc5, const float* __restrict__ sh5, float* __restrict__ out){
  int i = blockIdx.x*256 + threadIdx.x;
  int o = i & 1023;
  float sc = sc5[o];
  float v;
  if (sc >= 0.f){
    const float* p = &pmax[(size_t)i*8];
    v = p[0];
    #pragma unroll
    for (int u=1;u<8;u++) v = fmaxf(v, p[u]);
  } else {
    const float* p = &pmin[(size_t)i*8];
    v = p[0];
    #pragma unroll
    for (int u=1;u<8;u++) v = fminf(v, p[u]);
  }
  out[i] = lrelu(v*sc + sh5[o]);
}

extern "C" void kernel_launch(void* const* d_in, const int* in_sizes, int n_in,
                              void* d_out, int out_size, void* d_ws, size_t ws_size,
                              hipStream_t stream){
  const float* x  = (const float*)d_in[0];
  const float* w1 = (const float*)d_in[1];
  const float* g1 = (const float*)d_in[2];
  const float* b1 = (const float*)d_in[3];
  const float* w2 = (const float*)d_in[4];
  const float* g2 = (const float*)d_in[5];
  const float* b2 = (const float*)d_in[6];
  const float* w3 = (const float*)d_in[7];
  const float* g3 = (const float*)d_in[8];
  const float* b3 = (const float*)d_in[9];
  const float* w4 = (const float*)d_in[10];
  const float* g4 = (const float*)d_in[11];
  const float* b4 = (const float*)d_in[12];
  const float* w5 = (const float*)d_in[13];
  const float* g5 = (const float*)d_in[14];
  const float* b5 = (const float*)d_in[15];
  float* out = (float*)d_out;
  float* ws = (float*)d_ws;

  const size_t F_PD   = 0;
  const size_t F_XT0  = F_PD   + (size_t)BB*NN*NN;
  const size_t F_XC   = F_XT0  + (size_t)BB*NN*4;
  const size_t F_CHS  = F_XC   + (size_t)BB*NN*XCCH;
  const size_t F_CHQ  = F_CHS  + (size_t)NSLOT*256;
  const size_t F_SCL  = F_CHQ  + (size_t)NSLOT*256;
  const size_t F_SHF  = F_SCL  + 256;
  const size_t F_SQ   = F_SHF  + 256;
  const size_t F_IDX  = F_SQ   + (size_t)BB*NN;
  const size_t F_PMAX = F_IDX  + (size_t)BB*NN*KK;
  const size_t F_PMIN = F_PMAX + (size_t)BB*1024*8;
  const size_t F_PSUM = F_PMIN + (size_t)BB*1024*8;
  const size_t F_PSQ  = F_PSUM + (size_t)BB*1024*8;
  const size_t F_SC5  = F_PSQ  + (size_t)BB*1024*8;
  const size_t F_SH5  = F_SC5  + 1024;
  const size_t F_XCB  = F_SH5  + 1024;
  const size_t F_WB   = F_XCB  + (size_t)BB*NN*XCCH/2;
  const size_t F_PH   = F_WB   + 278528;
  const size_t F_PM   = F_PH   + 1048576;
  const size_t F_PL   = F_PM   + 1048576;

  float* pd    = ws + F_PD;
  float* ctrb  = pd;                          // alias pd (pd dead after k_topk)
  float* ymax  = pd + (size_t)16*1024*1024;
  float* ymin  = pd + (size_t)21*1024*1024;
  float* xt0   = ws + F_XT0;
  float* xc    = ws + F_XC;
  float* chsum = ws + F_CHS;
  float* chsq  = ws + F_CHQ;
  float* scl   = ws + F_SCL;
  float* shf   = ws + F_SHF;
  float* sqb   = ws + F_SQ;
  int*   idxb  = (int*)(ws + F_IDX);
  float* pmax  = ws + F_PMAX;
  float* pmin  = ws + F_PMIN;
  float* psum  = ws + F_PSUM;
  float* psq   = ws + F_PSQ;
  float* sc5   = ws + F_SC5;
  float* sh5   = ws + F_SH5;
  __hip_bfloat16* xcb = (__hip_bfloat16*)(ws + F_XCB);
  __hip_bfloat16* wb  = (__hip_bfloat16*)(ws + F_WB);
  __hip_bfloat16* w4d = wb;            // 256x128 (diff half of w4)
  __hip_bfloat16* w5b = wb + 32768;    // 1024x512
  _Float16* Ph  = (_Float16*)(ws + F_PH);
  _Float16* Pm  = (_Float16*)(ws + F_PM);
  _Float16* Pl  = (_Float16*)(ws + F_PL);

  (void)in_sizes; (void)n_in; (void)out_size; (void)ws_size;

  k_transpose<<<64, 256, 0, stream>>>(x, xt0);
  k_cvtw<<<(32768+255)/256,  256, 0, stream>>>(w4, w4d, 256, 128, 128, 128, 32768);
  k_cvtw<<<(524288+255)/256, 256, 0, stream>>>(w5, w5b, 512, 0, 512, 512, 524288);

  struct LayerP { const float* P; int stride; int Ci; int CiD; int Cpad;
                  const float* W; const float* g; const float* b; int Oi; int off; };
  LayerP L[4] = {
    { xt0,    4,   3,   4,   32,  w1, g1, b1,  64, 0   },
    { xc,     512, 64,  64,  64,  w2, g2, b2,  64, 64  },
    { xc+64,  512, 64,  64,  64,  w3, g3, b3, 128, 128 },
    { xc+128, 512, 128, 128, 128, w4, g4, b4, 256, 256 },
  };

  for (int l=0; l<4; ++l){
    int Cpad = L[l].Cpad, nchunk = Cpad/32;
    k_split<<<(BB*NN*Cpad+255)/256, 256, 0, stream>>>(L[l].P, L[l].stride, L[l].CiD, Cpad, Ph, Pm, Pl);
    k_sqs<<<64, 256, 0, stream>>>(Ph, Pm, Pl, Cpad, sqb);
    k_distm<<<dim3(16,16,8), 256, 0, stream>>>(Ph, Pm, Pl, Cpad, nchunk, sqb, pd);
    k_topk<<<BB*NN/4, 256, 0, stream>>>(pd, idxb);
    hipMemsetAsync(chsum, 0, (size_t)NSLOT*256*2*sizeof(float), stream);
    k_ctr<<<dim3(BB*NN/64, L[l].Oi/64), 256, 0, stream>>>(L[l].P, L[l].stride, L[l].Ci, L[l].W, 2*L[l].Ci, ctrb);
    if (l < 3){
      k_conv<<<dim3(BB*NN/8, L[l].Oi/64), 256, 0, stream>>>(L[l].P, L[l].stride, L[l].Ci, L[l].W, L[l].Oi,
                                                            idxb, ctrb, ymax, ymin, chsum, chsq);
    } else {
      k_convm<<<dim3(BB*NN/16, 4), 256, 0, stream>>>(xcb+128, XCCH, w4d, 4,
                                                     idxb, ctrb, ymax, ymin, chsum, chsq);
    }
    k_bnstats<<<1, 256, 0, stream>>>(chsum, chsq, L[l].g, L[l].b, scl, shf, L[l].Oi);
    k_apply<<<(BB*NN*L[l].Oi + 255)/256, 256, 0, stream>>>(ymax, ymin, scl, shf, xc, xcb, L[l].off, L[l].Oi);
  }

  k_conv5m<<<dim3(8, 16, BB), 256, 0, stream>>>(xcb, w5b, pmax, pmin, psum, psq);
  k_stats5<<<4, 256, 0, stream>>>(psum, psq, g5, b5, sc5, sh5);
  k_apply5<<<(BB*1024)/256, 256, 0, stream>>>(pmax, pmin, sc5, sh5, out);
}